// Round 1
// baseline (412.618 us; speedup 1.0000x reference)
//
#include <hip/hip_runtime.h>

// Problem constants (fixed by reference setup_inputs)
#define NB 8
#define NA 3
#define NH 160
#define NW 160
#define NCLS 80
#define NGT 32
#define NPB (NA * NH * NW)        // 76,800 cells per batch
#define TOTAL (NB * NPB)          // 614,400 cells
#define NBLK (TOTAL / 256)        // 2400 blocks
// Output: ONE flat float32 buffer, outputs concatenated in return order:
// p_bbox [8,76800,4] | cls_idx [8,76800] | score [8,76800] | loss [1]
#define OFF_CLSIDX (TOTAL * 4)    // 2,457,600  (f32 elements)
#define OFF_SCORE  (TOTAL * 5)    // 3,072,000
#define OFF_LOSS   (TOTAL * 6)    // 3,686,400

#define F4_PER_ROW 20             // 80 classes = 20 float4 per cell
#define LDS_ROW_F4 21             // +1 f4 pad to spread LDS banks

// Loss accumulator + completion ticket, owned by this .so.
// INVARIANT: both are 0 on kernel entry; the last-finishing block resets
// them to 0 before exiting, so every graph replay sees clean state.
__device__ float g_acc = 0.0f;
__device__ unsigned int g_cnt = 0u;

__device__ __forceinline__ float det_sigmoid(float x) { return 1.0f / (1.0f + expf(-x)); }
__device__ __forceinline__ float det_bce(float x, float t) {
    return fmaxf(x, 0.0f) - x * t + log1pf(expf(-fabsf(x)));
}
__device__ __forceinline__ float det_aw3(int a) { return a == 0 ? 10.0f : (a == 1 ? 16.0f : 33.0f); }
__device__ __forceinline__ float det_ah3(int a) { return a == 0 ? 13.0f : (a == 1 ? 30.0f : 23.0f); }

// gt_mask layout detection (u8 bool vs int32), deterministic each call.
// 64 uniform dword loads, wave-broadcast from L2 — cheap enough to call
// redundantly per thread that needs it (avoids an s_u8 staging barrier).
__device__ __forceinline__ bool det_mask_is_u8(const void* p) {
    const unsigned int* w = (const unsigned int*)p;
    unsigned int acc = 0;
#pragma unroll
    for (int k = 0; k < 64; k++) acc |= (w[k] & 0xFFFFFF00u);
    return acc != 0;
}
__device__ __forceinline__ bool det_mask_at(const void* p, bool u8mode, int idx) {
    return u8mode ? (((const unsigned char*)p)[idx] != 0)
                  : (((const int*)p)[idx] != 0);
}

// Per-(b,g) target losses (xy, wh, cls) — one thread each (256 = 8*32).
// Executed only by block 0; returns 0 for invalid GTs so the result can be
// folded straight into the block's conf-loss wave reduction (no extra atomics).
__device__ __forceinline__ float det_gt_loss(int tid,
        const float* __restrict__ t_bbox,
        const float* __restrict__ cls_logits,
        const float* __restrict__ gt_bboxes,
        const int* __restrict__ gt_cls,
        const void* __restrict__ gt_mask) {
    bool u8mode = det_mask_is_u8(gt_mask);
    int b = tid >> 5;
    int g = tid & 31;
    float4 gtb = ((const float4*)gt_bboxes)[b * NGT + g];
    float cx = gtb.x, cy = gtb.y, gw = gtb.z, gh = gtb.w;

    const float aw9[9] = {10.f,16.f,33.f,30.f,62.f,59.f,116.f,156.f,373.f};
    const float ah9[9] = {13.f,30.f,23.f,61.f,45.f,119.f,90.f,198.f,326.f};
    float garea = gw * gh;
    int aidx = 0;
    float best = -1.0f;
#pragma unroll
    for (int k = 0; k < 9; k++) {
        float inter = fminf(gw, aw9[k]) * fminf(gh, ah9[k]);
        float uni = garea + aw9[k] * ah9[k] - inter;
        float r = inter / (uni + 1e-16f);
        if (r > best) { best = r; aidx = k; }
    }
    bool valid = det_mask_at(gt_mask, u8mode, b * NGT + g) && (aidx < NA);
    int ta = aidx % NA;
    int ti = min(max((int)(cx * 0.125f), 0), NW - 1);
    int tj = min(max((int)(cy * 0.125f), 0), NH - 1);
    size_t cell = ((size_t)(b * NA + ta) * NH + tj) * NW + ti;

    float4 tb = ((const float4*)t_bbox)[cell];
    float fx = cx * 0.125f; fx -= floorf(fx);
    float fy = cy * 0.125f; fy -= floorf(fy);
    float tx = (fx + 0.5f) * 0.5f;
    float ty = (fy + 0.5f) * 0.5f;
    float tw = sqrtf(gw / det_aw3(ta)) * 0.5f;
    float th = sqrtf(gh / det_ah3(ta)) * 0.5f;

    float l = det_bce(tb.x, tx) + det_bce(tb.y, ty) +
              det_bce(tb.z, tw) + det_bce(tb.w, th);

    const float4* cl = (const float4*)(cls_logits + cell * NCLS);
    int tc = gt_cls[b * NGT + g];
    float lc = 0.0f;
#pragma unroll
    for (int c4 = 0; c4 < NCLS / 4; c4++) {
        float4 v = cl[c4];
        int c = c4 * 4;
        lc += det_bce(v.x, (c + 0 == tc) ? 1.0f : 0.0f);
        lc += det_bce(v.y, (c + 1 == tc) ? 1.0f : 0.0f);
        lc += det_bce(v.z, (c + 2 == tc) ? 1.0f : 0.0f);
        lc += det_bce(v.w, (c + 3 == tc) ? 1.0f : 0.0f);
    }
    l += lc * (1.0f / NCLS);
    return valid ? l : 0.0f;
}

// ---------------- Single fused kernel --------------------------------------
// Block = 256 threads (4 waves) = 256 cells; NPB % 256 == 0 so blocks never
// straddle batches.
//   Phase 1: bbox decode + IoU + conf-BCE (all coalesced).
//   Block 0 only: GT target losses folded into the conf-loss reduce chain.
//   Phase 2: class argmax via LDS-staged coalesced tile loads. s_cls is
//     per-WAVE private and DS ops execute in wave order, so NO barriers are
//     needed in the tile loop (the old version had 8 — removed; lets the
//     compiler hoist tile it+1's global loads over tile it's LDS scan).
//   Epilogue: one barrier, block partial -> global atomic, last-block ticket
//     writes the loss and resets g_acc/g_cnt for the next graph replay.
__global__ __launch_bounds__(256) void det_all_k(
    const float* __restrict__ t_bbox,
    const float* __restrict__ conf_logits,
    const float* __restrict__ cls_logits,
    const float* __restrict__ gt_bboxes,
    const int* __restrict__ gt_cls,
    const void* __restrict__ gt_mask,
    float* __restrict__ out) {
    __shared__ float4 s_cls[4][16 * LDS_ROW_F4];   // 21.5 KB, per-wave tiles
    __shared__ float4 s_box[NGT];                  // x1,y1,x2,y2 (packed: 2 LDS
    __shared__ float2 s_am[NGT];                   //  reads/GT instead of 6)
    __shared__ float s_part[4];

    int tid = threadIdx.x;
    int blockCell = blockIdx.x * 256;
    int gid = blockCell + tid;
    int b = gid / NPB;          // uniform within a block
    int r = gid % NPB;

    if (tid < NGT) {
        bool u8mode = det_mask_is_u8(gt_mask);
        float4 gtb = ((const float4*)gt_bboxes)[b * NGT + tid];
        float4 bx;
        bx.x = gtb.x - gtb.z * 0.5f;   // x1
        bx.y = gtb.y - gtb.w * 0.5f;   // y1
        bx.z = gtb.x + gtb.z * 0.5f;   // x2
        bx.w = gtb.y + gtb.w * 0.5f;   // y2
        s_box[tid] = bx;
        float2 am;
        am.x = gtb.z * gtb.w;
        am.y = det_mask_at(gt_mask, u8mode, b * NGT + tid) ? 1.0f : 0.0f;
        s_am[tid] = am;
    }
    __syncthreads();   // barrier #1 (of 2): GT tile staged

    // ---- Phase 1: bbox decode + IoU + conf loss (thread t <-> cell gid) ----
    int a   = r / (NH * NW);
    int rem = r % (NH * NW);
    int j   = rem / NW;
    int i   = rem % NW;

    float4 tb = ((const float4*)t_bbox)[gid];
    float s0 = det_sigmoid(tb.x), s1 = det_sigmoid(tb.y);
    float s2 = det_sigmoid(tb.z), s3 = det_sigmoid(tb.w);
    float px = (s0 * 2.0f - 0.5f + (float)i) * 8.0f;
    float py = (s1 * 2.0f - 0.5f + (float)j) * 8.0f;
    float sw = s2 * 2.0f, sh = s3 * 2.0f;
    float pw = sw * sw * det_aw3(a);
    float ph = sh * sh * det_ah3(a);
    float4 pb; pb.x = px; pb.y = py; pb.z = pw; pb.w = ph;
    ((float4*)out)[gid] = pb;

    float px1 = px - pw * 0.5f, px2 = px + pw * 0.5f;
    float py1 = py - ph * 0.5f, py2 = py + ph * 0.5f;
    float parea = pw * ph;
    float maxiou = 0.0f;
#pragma unroll
    for (int g = 0; g < NGT; g++) {
        float4 bx = s_box[g];
        float2 am = s_am[g];
        float iw = fmaxf(fminf(px2, bx.z) - fmaxf(px1, bx.x), 0.0f);
        float ih = fmaxf(fminf(py2, bx.w) - fmaxf(py1, bx.y), 0.0f);
        float inter = iw * ih;
        float uni = parea + am.x - inter;
        float iou = inter / (uni + 1e-16f);
        maxiou = fmaxf(maxiou, (am.y != 0.0f) ? iou : 0.0f);
    }

    float confl = conf_logits[gid];
    float sconf = det_sigmoid(confl);          // kept for phase 2 via shuffle
    float lconf = det_bce(confl, maxiou);

    // Block 0 carries the GT target losses — folded into the same reduction.
    if (blockIdx.x == 0)
        lconf += det_gt_loss(tid, t_bbox, cls_logits, gt_bboxes, gt_cls, gt_mask);

#pragma unroll
    for (int off = 32; off > 0; off >>= 1) lconf += __shfl_down(lconf, off, 64);
    int w = tid >> 6, l = tid & 63;
    if (l == 0) s_part[w] = lconf;   // read after the epilogue barrier

    // ---- Phase 2: class argmax + score, LDS-staged coalesced, barrier-free -
    int cl_ = l >> 2;            // local cell within 16-row tile
    int q   = l & 3;             // quad lane: scans cols [5q, 5q+5)
    const float4* g4 = (const float4*)cls_logits;
    int wbase = blockCell + w * 64;            // first cell of this wave

#pragma unroll
    for (int it = 0; it < 4; ++it) {
        int tileCell = wbase + it * 16;
        size_t f4base = (size_t)tileCell * F4_PER_ROW;
        // s_cls[w] is this wave's private slice; per-wave DS ordering makes
        // the previous tile's reads complete before these writes land.
#pragma unroll
        for (int k = 0; k < 5; ++k) {          // 320 consecutive f4 per tile
            int f = k * 64 + l;
            float4 v = g4[f4base + f];
            int rr = f / F4_PER_ROW;
            int cc = f - rr * F4_PER_ROW;
            s_cls[w][rr * LDS_ROW_F4 + cc] = v;
        }

        float mx = -1e30f;
        int mi = 0;
#pragma unroll
        for (int k = 0; k < 5; ++k) {
            int col = q * 5 + k;               // ascending within lane
            float4 v = s_cls[w][cl_ * LDS_ROW_F4 + col];
            int c = col * 4;
            if (v.x > mx) { mx = v.x; mi = c + 0; }
            if (v.y > mx) { mx = v.y; mi = c + 1; }
            if (v.z > mx) { mx = v.z; mi = c + 2; }
            if (v.w > mx) { mx = v.w; mi = c + 3; }
        }
        // quad reduce: lexicographic (value, lower index) == jnp first-max
#pragma unroll
        for (int s = 1; s < 4; s <<= 1) {
            float ov = __shfl_xor(mx, s, 64);
            int   oi = __shfl_xor(mi, s, 64);
            if (ov > mx || (ov == mx && oi < mi)) { mx = ov; mi = oi; }
        }
        // sigmoid(conf) of this tile's cell lives in lane it*16+cl_ (phase 1)
        float sc = __shfl(sconf, it * 16 + cl_, 64);
        if (q == 0) {
            int cellg = tileCell + cl_;
            out[OFF_CLSIDX + cellg] = (float)mi;
            out[OFF_SCORE  + cellg] = sc * det_sigmoid(mx);
        }
    }

    // ---- Epilogue: block partial -> device atomic; last block finalizes ----
    __syncthreads();   // barrier #2 (of 2): s_part ready
    if (tid == 0) {
        atomicAdd(&g_acc, s_part[0] + s_part[1] + s_part[2] + s_part[3]);
        __threadfence();                       // adds visible before ticket
        unsigned int t = atomicAdd(&g_cnt, 1u);
        if (t == NBLK - 1) {
            __threadfence();
            float tot = atomicAdd(&g_acc, 0.0f);   // coherent RMW read
            out[OFF_LOSS] = tot * (1.0f / NB);
            // reset for the next graph replay (keeps the entry invariant)
            atomicExch(&g_acc, 0.0f);
            atomicExch(&g_cnt, 0u);
        }
    }
}

extern "C" void kernel_launch(void* const* d_in, const int* in_sizes, int n_in,
                              void* d_out, int out_size, void* d_ws, size_t ws_size,
                              hipStream_t stream) {
    (void)in_sizes; (void)n_in; (void)out_size; (void)d_ws; (void)ws_size;
    const float* t_bbox      = (const float*)d_in[0];
    const float* conf_logits = (const float*)d_in[1];
    const float* cls_logits  = (const float*)d_in[2];
    const float* gt_bboxes   = (const float*)d_in[3];
    const int*   gt_cls      = (const int*)d_in[4];
    const void*  gt_mask     = (const void*)d_in[5];  // layout auto-detected
    float* out = (float*)d_out;                       // float32 per reference

    det_all_k<<<NBLK, 256, 0, stream>>>(t_bbox, conf_logits, cls_logits,
                                        gt_bboxes, gt_cls, gt_mask, out);
}

// Round 2
// 321.813 us; speedup vs baseline: 1.2822x; 1.2822x over previous
//
#include <hip/hip_runtime.h>

// Problem constants (fixed by reference setup_inputs)
#define NB 8
#define NA 3
#define NH 160
#define NW 160
#define NCLS 80
#define NGT 32
#define NPB (NA * NH * NW)        // 76,800 cells per batch
#define TOTAL (NB * NPB)          // 614,400 cells
#define NBLK (TOTAL / 256)        // 2400 blocks
// Output: ONE flat float32 buffer, outputs concatenated in return order:
// p_bbox [8,76800,4] | cls_idx [8,76800] | score [8,76800] | loss [1]
#define OFF_CLSIDX (TOTAL * 4)    // 2,457,600  (f32 elements)
#define OFF_SCORE  (TOTAL * 5)    // 3,072,000
#define OFF_LOSS   (TOTAL * 6)    // 3,686,400

#define F4_PER_ROW 20             // 80 classes = 20 float4 per cell
#define LDS_ROW_F4 21             // +1 f4 pad to spread LDS banks

// Loss accumulator owned by this .so.
// INVARIANT: 0 on kernel entry. det_fin_k (same graph, after det_all_k)
// reads it and resets it to 0, so every graph replay sees clean state.
// NO device fences anywhere — coherence comes from kernel boundaries
// (round-1 lesson: per-block __threadfence on multi-XCD gfx950 emits L2
// writebacks and cost ~100 us across 2400 blocks).
__device__ float g_acc = 0.0f;

__device__ __forceinline__ float det_sigmoid(float x) { return 1.0f / (1.0f + expf(-x)); }
__device__ __forceinline__ float det_bce(float x, float t) {
    return fmaxf(x, 0.0f) - x * t + log1pf(expf(-fabsf(x)));
}
__device__ __forceinline__ float det_aw3(int a) { return a == 0 ? 10.0f : (a == 1 ? 16.0f : 33.0f); }
__device__ __forceinline__ float det_ah3(int a) { return a == 0 ? 13.0f : (a == 1 ? 30.0f : 23.0f); }

// gt_mask layout detection (u8 bool vs int32), deterministic each call.
// 64 uniform dword loads, wave-broadcast from L1/L2 — cheap enough to call
// redundantly in the few threads that need it.
__device__ __forceinline__ bool det_mask_is_u8(const void* p) {
    const unsigned int* w = (const unsigned int*)p;
    unsigned int acc = 0;
#pragma unroll
    for (int k = 0; k < 64; k++) acc |= (w[k] & 0xFFFFFF00u);
    return acc != 0;
}
__device__ __forceinline__ bool det_mask_at(const void* p, bool u8mode, int idx) {
    return u8mode ? (((const unsigned char*)p)[idx] != 0)
                  : (((const int*)p)[idx] != 0);
}

// Per-(b,g) target losses (xy, wh, cls) — one thread each (256 = 8*32).
// Executed only by block 0; returns 0 for invalid GTs so the result folds
// straight into the block's conf-loss wave reduction (no extra atomics).
// (Verified correct in round 1: absmax unchanged vs 4-kernel version.)
__device__ __forceinline__ float det_gt_loss(int tid,
        const float* __restrict__ t_bbox,
        const float* __restrict__ cls_logits,
        const float* __restrict__ gt_bboxes,
        const int* __restrict__ gt_cls,
        const void* __restrict__ gt_mask) {
    bool u8mode = det_mask_is_u8(gt_mask);
    int b = tid >> 5;
    int g = tid & 31;
    float4 gtb = ((const float4*)gt_bboxes)[b * NGT + g];
    float cx = gtb.x, cy = gtb.y, gw = gtb.z, gh = gtb.w;

    const float aw9[9] = {10.f,16.f,33.f,30.f,62.f,59.f,116.f,156.f,373.f};
    const float ah9[9] = {13.f,30.f,23.f,61.f,45.f,119.f,90.f,198.f,326.f};
    float garea = gw * gh;
    int aidx = 0;
    float best = -1.0f;
#pragma unroll
    for (int k = 0; k < 9; k++) {
        float inter = fminf(gw, aw9[k]) * fminf(gh, ah9[k]);
        float uni = garea + aw9[k] * ah9[k] - inter;
        float r = inter / (uni + 1e-16f);
        if (r > best) { best = r; aidx = k; }
    }
    bool valid = det_mask_at(gt_mask, u8mode, b * NGT + g) && (aidx < NA);
    int ta = aidx % NA;
    int ti = min(max((int)(cx * 0.125f), 0), NW - 1);
    int tj = min(max((int)(cy * 0.125f), 0), NH - 1);
    size_t cell = ((size_t)(b * NA + ta) * NH + tj) * NW + ti;

    float4 tb = ((const float4*)t_bbox)[cell];
    float fx = cx * 0.125f; fx -= floorf(fx);
    float fy = cy * 0.125f; fy -= floorf(fy);
    float tx = (fx + 0.5f) * 0.5f;
    float ty = (fy + 0.5f) * 0.5f;
    float tw = sqrtf(gw / det_aw3(ta)) * 0.5f;
    float th = sqrtf(gh / det_ah3(ta)) * 0.5f;

    float l = det_bce(tb.x, tx) + det_bce(tb.y, ty) +
              det_bce(tb.z, tw) + det_bce(tb.w, th);

    const float4* cl = (const float4*)(cls_logits + cell * NCLS);
    int tc = gt_cls[b * NGT + g];
    float lc = 0.0f;
#pragma unroll
    for (int c4 = 0; c4 < NCLS / 4; c4++) {
        float4 v = cl[c4];
        int c = c4 * 4;
        lc += det_bce(v.x, (c + 0 == tc) ? 1.0f : 0.0f);
        lc += det_bce(v.y, (c + 1 == tc) ? 1.0f : 0.0f);
        lc += det_bce(v.z, (c + 2 == tc) ? 1.0f : 0.0f);
        lc += det_bce(v.w, (c + 3 == tc) ? 1.0f : 0.0f);
    }
    l += lc * (1.0f / NCLS);
    return valid ? l : 0.0f;
}

// ---------------- Main fused kernel ----------------------------------------
// Block = 256 threads (4 waves) = 256 cells; NPB % 256 == 0 so blocks never
// straddle batches. Structure = round-0's proven barrier rhythm:
//   Phase 1: bbox decode + IoU + conf-BCE; block partial -> atomic mid-kernel.
//   Phase 2: class argmax, LDS-staged coalesced, 2 barriers per tile.
// NEW vs round 0: register double-buffer of the class tile — tile it+1's
// 5 global_load_dwordx4 are issued right after tile it's ds_write, so HBM
// latency hides under the scan + barriers instead of a per-tile vmcnt(0).
__global__ __launch_bounds__(256) void det_all_k(
    const float* __restrict__ t_bbox,
    const float* __restrict__ conf_logits,
    const float* __restrict__ cls_logits,
    const float* __restrict__ gt_bboxes,
    const int* __restrict__ gt_cls,
    const void* __restrict__ gt_mask,
    float* __restrict__ out) {
    __shared__ float4 s_cls[4][16 * LDS_ROW_F4];   // 21.5 KB, per-wave tiles
    __shared__ float4 s_box[NGT];                  // x1,y1,x2,y2 packed: 2 LDS
    __shared__ float2 s_am[NGT];                   //  reads/GT instead of 6
    __shared__ float s_part[4];

    int tid = threadIdx.x;
    int blockCell = blockIdx.x * 256;
    int gid = blockCell + tid;
    int b = gid / NPB;          // uniform within a block
    int r = gid % NPB;

    if (tid < NGT) {
        bool u8mode = det_mask_is_u8(gt_mask);
        float4 gtb = ((const float4*)gt_bboxes)[b * NGT + tid];
        float4 bx;
        bx.x = gtb.x - gtb.z * 0.5f;   // x1
        bx.y = gtb.y - gtb.w * 0.5f;   // y1
        bx.z = gtb.x + gtb.z * 0.5f;   // x2
        bx.w = gtb.y + gtb.w * 0.5f;   // y2
        s_box[tid] = bx;
        float2 am;
        am.x = gtb.z * gtb.w;
        am.y = det_mask_at(gt_mask, u8mode, b * NGT + tid) ? 1.0f : 0.0f;
        s_am[tid] = am;
    }
    __syncthreads();   // GT tile staged

    // ---- Phase 1: bbox decode + IoU + conf loss (thread t <-> cell gid) ----
    int a   = r / (NH * NW);
    int rem = r % (NH * NW);
    int j   = rem / NW;
    int i   = rem % NW;

    float4 tb = ((const float4*)t_bbox)[gid];
    float s0 = det_sigmoid(tb.x), s1 = det_sigmoid(tb.y);
    float s2 = det_sigmoid(tb.z), s3 = det_sigmoid(tb.w);
    float px = (s0 * 2.0f - 0.5f + (float)i) * 8.0f;
    float py = (s1 * 2.0f - 0.5f + (float)j) * 8.0f;
    float sw = s2 * 2.0f, sh = s3 * 2.0f;
    float pw = sw * sw * det_aw3(a);
    float ph = sh * sh * det_ah3(a);
    float4 pb; pb.x = px; pb.y = py; pb.z = pw; pb.w = ph;
    ((float4*)out)[gid] = pb;

    float px1 = px - pw * 0.5f, px2 = px + pw * 0.5f;
    float py1 = py - ph * 0.5f, py2 = py + ph * 0.5f;
    float parea = pw * ph;
    float maxiou = 0.0f;
#pragma unroll
    for (int g = 0; g < NGT; g++) {
        float4 bx = s_box[g];
        float2 am = s_am[g];
        float iw = fmaxf(fminf(px2, bx.z) - fmaxf(px1, bx.x), 0.0f);
        float ih = fmaxf(fminf(py2, bx.w) - fmaxf(py1, bx.y), 0.0f);
        float inter = iw * ih;
        float uni = parea + am.x - inter;
        float iou = inter / (uni + 1e-16f);
        maxiou = fmaxf(maxiou, (am.y != 0.0f) ? iou : 0.0f);
    }

    float confl = conf_logits[gid];
    float sconf = det_sigmoid(confl);          // kept for phase 2 via shuffle
    float lconf = det_bce(confl, maxiou);

    // Block 0 carries the GT target losses — folded into the same reduction.
    if (blockIdx.x == 0)
        lconf += det_gt_loss(tid, t_bbox, cls_logits, gt_bboxes, gt_cls, gt_mask);

#pragma unroll
    for (int off = 32; off > 0; off >>= 1) lconf += __shfl_down(lconf, off, 64);
    int w = tid >> 6, l = tid & 63;
    if (l == 0) s_part[w] = lconf;
    __syncthreads();
    if (tid == 0)
        atomicAdd(&g_acc, s_part[0] + s_part[1] + s_part[2] + s_part[3]);

    // ---- Phase 2: class argmax + score, LDS-staged, reg double-buffered ----
    int cl_ = l >> 2;            // local cell within 16-row tile
    int q   = l & 3;             // quad lane: scans cols [5q, 5q+5)
    const float4* g4 = (const float4*)cls_logits;
    int wbase = blockCell + w * 64;            // first cell of this wave

    float4 rbuf[5];              // in-flight tile (statically indexed only)
    {
        size_t f4base = (size_t)wbase * F4_PER_ROW;
#pragma unroll
        for (int k = 0; k < 5; ++k) rbuf[k] = g4[f4base + k * 64 + l];
    }

#pragma unroll
    for (int it = 0; it < 4; ++it) {
        __syncthreads();                       // LDS tile reuse guard
        // stage current tile from regs (vmcnt satisfied long ago)
#pragma unroll
        for (int k = 0; k < 5; ++k) {          // 320 consecutive f4 per tile
            int f = k * 64 + l;
            int rr = f / F4_PER_ROW;
            int cc = f - rr * F4_PER_ROW;
            s_cls[w][rr * LDS_ROW_F4 + cc] = rbuf[k];
        }
        // issue next tile's loads — latency hides under scan + barriers
        if (it < 3) {
            size_t f4n = (size_t)(wbase + (it + 1) * 16) * F4_PER_ROW;
#pragma unroll
            for (int k = 0; k < 5; ++k) rbuf[k] = g4[f4n + k * 64 + l];
        }
        __syncthreads();                       // tile staged

        float mx = -1e30f;
        int mi = 0;
#pragma unroll
        for (int k = 0; k < 5; ++k) {
            int col = q * 5 + k;               // ascending within lane
            float4 v = s_cls[w][cl_ * LDS_ROW_F4 + col];
            int c = col * 4;
            if (v.x > mx) { mx = v.x; mi = c + 0; }
            if (v.y > mx) { mx = v.y; mi = c + 1; }
            if (v.z > mx) { mx = v.z; mi = c + 2; }
            if (v.w > mx) { mx = v.w; mi = c + 3; }
        }
        // quad reduce: lexicographic (value, lower index) == jnp first-max
#pragma unroll
        for (int s = 1; s < 4; s <<= 1) {
            float ov = __shfl_xor(mx, s, 64);
            int   oi = __shfl_xor(mi, s, 64);
            if (ov > mx || (ov == mx && oi < mi)) { mx = ov; mi = oi; }
        }
        // sigmoid(conf) of this tile's cell lives in lane it*16+cl_ (phase 1)
        int tileCell = wbase + it * 16;
        float sc = __shfl(sconf, it * 16 + cl_, 64);
        if (q == 0) {
            int cellg = tileCell + cl_;
            out[OFF_CLSIDX + cellg] = (float)mi;
            out[OFF_SCORE  + cellg] = sc * det_sigmoid(mx);
        }
    }
}

// ---------------- Finalize: write loss, reset accumulator ------------------
// Kernel boundary provides device-wide visibility of det_all_k's atomics
// (round-0-proven). Resetting here keeps the entry invariant for the next
// graph replay without a separate zero kernel.
__global__ void det_fin_k(float* __restrict__ out) {
    out[OFF_LOSS] = g_acc * (1.0f / NB);
    g_acc = 0.0f;
}

extern "C" void kernel_launch(void* const* d_in, const int* in_sizes, int n_in,
                              void* d_out, int out_size, void* d_ws, size_t ws_size,
                              hipStream_t stream) {
    (void)in_sizes; (void)n_in; (void)out_size; (void)d_ws; (void)ws_size;
    const float* t_bbox      = (const float*)d_in[0];
    const float* conf_logits = (const float*)d_in[1];
    const float* cls_logits  = (const float*)d_in[2];
    const float* gt_bboxes   = (const float*)d_in[3];
    const int*   gt_cls      = (const int*)d_in[4];
    const void*  gt_mask     = (const void*)d_in[5];  // layout auto-detected
    float* out = (float*)d_out;                       // float32 per reference

    det_all_k<<<NBLK, 256, 0, stream>>>(t_bbox, conf_logits, cls_logits,
                                        gt_bboxes, gt_cls, gt_mask, out);
    det_fin_k<<<1, 1, 0, stream>>>(out);
}

// Round 3
// 297.888 us; speedup vs baseline: 1.3851x; 1.0803x over previous
//
#include <hip/hip_runtime.h>

// Problem constants (fixed by reference setup_inputs)
#define NB 8
#define NA 3
#define NH 160
#define NW 160
#define NCLS 80
#define NGT 32
#define NPB (NA * NH * NW)        // 76,800 cells per batch
#define TOTAL (NB * NPB)          // 614,400 cells
#define NBLK (TOTAL / 256)        // 2400 blocks
// Output: ONE flat float32 buffer, outputs concatenated in return order:
// p_bbox [8,76800,4] | cls_idx [8,76800] | score [8,76800] | loss [1]
#define OFF_CLSIDX (TOTAL * 4)    // 2,457,600  (f32 elements)
#define OFF_SCORE  (TOTAL * 5)    // 3,072,000
#define OFF_LOSS   (TOTAL * 6)    // 3,686,400

#define F4_PER_ROW 20             // 80 classes = 20 float4 per cell
// NOTE: tile is UNPADDED [16][20] f4 — global_load_lds writes linearly
// (base + lane*16B), padding is impossible (m104). Bank spread on the scan
// read is ~equivalent to the old padded layout (8 groups); measured
// conflict cost was ~3 us total — acceptable.

// Loss accumulator owned by this .so.
// INVARIANT: 0 on kernel entry. det_fin_k (same graph, after det_all_k)
// reads it and resets it, so every graph replay sees clean state.
// NO device fences anywhere (round-1 lesson: per-block __threadfence on
// multi-XCD gfx950 cost ~90 us across 2400 blocks). Kernel boundary
// provides coherence for g_acc (round-0-proven).
__device__ float g_acc = 0.0f;

__device__ __forceinline__ float det_sigmoid(float x) { return 1.0f / (1.0f + expf(-x)); }
__device__ __forceinline__ float det_bce(float x, float t) {
    return fmaxf(x, 0.0f) - x * t + log1pf(expf(-fabsf(x)));
}
__device__ __forceinline__ float det_aw3(int a) { return a == 0 ? 10.0f : (a == 1 ? 16.0f : 33.0f); }
__device__ __forceinline__ float det_ah3(int a) { return a == 0 ? 13.0f : (a == 1 ? 30.0f : 23.0f); }

// gt_mask layout detection (u8 bool vs int32), deterministic each call.
__device__ __forceinline__ bool det_mask_is_u8(const void* p) {
    const unsigned int* w = (const unsigned int*)p;
    unsigned int acc = 0;
#pragma unroll
    for (int k = 0; k < 64; k++) acc |= (w[k] & 0xFFFFFF00u);
    return acc != 0;
}
__device__ __forceinline__ bool det_mask_at(const void* p, bool u8mode, int idx) {
    return u8mode ? (((const unsigned char*)p)[idx] != 0)
                  : (((const int*)p)[idx] != 0);
}

// Per-(b,g) target losses (xy, wh, cls) — one thread each (256 = 8*32).
// Block 0 only; returns 0 for invalid GTs so it folds into the conf-loss
// wave reduction. (Verified correct in rounds 1-2.)
__device__ __forceinline__ float det_gt_loss(int tid,
        const float* __restrict__ t_bbox,
        const float* __restrict__ cls_logits,
        const float* __restrict__ gt_bboxes,
        const int* __restrict__ gt_cls,
        const void* __restrict__ gt_mask) {
    bool u8mode = det_mask_is_u8(gt_mask);
    int b = tid >> 5;
    int g = tid & 31;
    float4 gtb = ((const float4*)gt_bboxes)[b * NGT + g];
    float cx = gtb.x, cy = gtb.y, gw = gtb.z, gh = gtb.w;

    const float aw9[9] = {10.f,16.f,33.f,30.f,62.f,59.f,116.f,156.f,373.f};
    const float ah9[9] = {13.f,30.f,23.f,61.f,45.f,119.f,90.f,198.f,326.f};
    float garea = gw * gh;
    int aidx = 0;
    float best = -1.0f;
#pragma unroll
    for (int k = 0; k < 9; k++) {
        float inter = fminf(gw, aw9[k]) * fminf(gh, ah9[k]);
        float uni = garea + aw9[k] * ah9[k] - inter;
        float r = inter / (uni + 1e-16f);
        if (r > best) { best = r; aidx = k; }
    }
    bool valid = det_mask_at(gt_mask, u8mode, b * NGT + g) && (aidx < NA);
    int ta = aidx % NA;
    int ti = min(max((int)(cx * 0.125f), 0), NW - 1);
    int tj = min(max((int)(cy * 0.125f), 0), NH - 1);
    size_t cell = ((size_t)(b * NA + ta) * NH + tj) * NW + ti;

    float4 tb = ((const float4*)t_bbox)[cell];
    float fx = cx * 0.125f; fx -= floorf(fx);
    float fy = cy * 0.125f; fy -= floorf(fy);
    float tx = (fx + 0.5f) * 0.5f;
    float ty = (fy + 0.5f) * 0.5f;
    float tw = sqrtf(gw / det_aw3(ta)) * 0.5f;
    float th = sqrtf(gh / det_ah3(ta)) * 0.5f;

    float l = det_bce(tb.x, tx) + det_bce(tb.y, ty) +
              det_bce(tb.z, tw) + det_bce(tb.w, th);

    const float4* cl = (const float4*)(cls_logits + cell * NCLS);
    int tc = gt_cls[b * NGT + g];
    float lc = 0.0f;
#pragma unroll
    for (int c4 = 0; c4 < NCLS / 4; c4++) {
        float4 v = cl[c4];
        int c = c4 * 4;
        lc += det_bce(v.x, (c + 0 == tc) ? 1.0f : 0.0f);
        lc += det_bce(v.y, (c + 1 == tc) ? 1.0f : 0.0f);
        lc += det_bce(v.z, (c + 2 == tc) ? 1.0f : 0.0f);
        lc += det_bce(v.w, (c + 3 == tc) ? 1.0f : 0.0f);
    }
    l += lc * (1.0f / NCLS);
    return valid ? l : 0.0f;
}

// Issue one 16-row class tile (320 consecutive float4) as 5 direct
// global->LDS DMA loads (width 16B). No VGPR staging => no spill possible.
// LDS dest is wave-uniform base + lane*16B => slot k*64+l holds global f4
// (f4base + k*64 + l): identity map, coalesced 1024B per instruction.
__device__ __forceinline__ void det_issue_tile(const float4* g4, float4* ldsbase,
                                               size_t f4base, int l) {
#pragma unroll
    for (int k = 0; k < 5; ++k) {
        __builtin_amdgcn_global_load_lds(
            (const __attribute__((address_space(1))) void*)(g4 + f4base + k * 64 + l),
            (__attribute__((address_space(3))) void*)(ldsbase + k * 64),
            16, 0, 0);
    }
}

// Scan one staged tile: 4 lanes/cell argmax over 80 classes + quad reduce
// (lexicographic (value, lower index) == jnp first-max), then score store.
__device__ __forceinline__ void det_scan_tile(const float4* tile, int cl_, int q,
                                              int tileCell, float sconf, int it,
                                              float* __restrict__ out) {
    float mx = -1e30f;
    int mi = 0;
#pragma unroll
    for (int k = 0; k < 5; ++k) {
        int col = q * 5 + k;               // ascending within lane
        float4 v = tile[cl_ * F4_PER_ROW + col];
        int c = col * 4;
        if (v.x > mx) { mx = v.x; mi = c + 0; }
        if (v.y > mx) { mx = v.y; mi = c + 1; }
        if (v.z > mx) { mx = v.z; mi = c + 2; }
        if (v.w > mx) { mx = v.w; mi = c + 3; }
    }
#pragma unroll
    for (int s = 1; s < 4; s <<= 1) {
        float ov = __shfl_xor(mx, s, 64);
        int   oi = __shfl_xor(mi, s, 64);
        if (ov > mx || (ov == mx && oi < mi)) { mx = ov; mi = oi; }
    }
    // sigmoid(conf) of this tile's cell lives in lane it*16+cl_ (phase 1)
    float sc = __shfl(sconf, it * 16 + cl_, 64);
    if (q == 0) {                          // 16 lanes, 64B contiguous stores
        int cellg = tileCell + cl_;
        out[OFF_CLSIDX + cellg] = (float)mi;
        out[OFF_SCORE  + cellg] = sc * det_sigmoid(mx);
    }
}

// Counted vmcnt wait (never 0 mid-pipeline) + sched fence so ds_reads can't
// hoist above it (rule: compiler may move ops past inline-asm waitcnt).
#define DET_WAITVM(N) do { \
    asm volatile("s_waitcnt vmcnt(" #N ")" ::: "memory"); \
    __builtin_amdgcn_sched_barrier(0); \
} while (0)

// ---------------- Main fused kernel ----------------------------------------
// Block = 256 threads (4 waves) = 256 cells; NPB % 256 == 0.
//   Phase 1: bbox decode + IoU + conf-BCE (coalesced); block 0 folds GT
//            losses into the same reduce chain. Tiles 0/1 of phase 2 are
//            DMA-issued BEFORE the IoU loop so ~1100 VALU cycles hide HBM.
//   Phase 2: class argmax, per-wave double-buffered global->LDS DMA tiles,
//            counted vmcnt(5) waits, ZERO barriers (s_cls[w] is wave-private).
//   Wait-count safety: vmcnt retires in issue order (m135). Each wait's N
//   counts only LOADS issued after the tile it needs; stores / block-0 GT
//   loads issued in between only make the wait more conservative.
__global__ __launch_bounds__(256) void det_all_k(
    const float* __restrict__ t_bbox,
    const float* __restrict__ conf_logits,
    const float* __restrict__ cls_logits,
    const float* __restrict__ gt_bboxes,
    const int* __restrict__ gt_cls,
    const void* __restrict__ gt_mask,
    float* __restrict__ out) {
    __shared__ float4 s_cls[4][2][16 * F4_PER_ROW];  // 40 KB: 4 waves x 2 bufs
    __shared__ float4 s_box[NGT];                    // x1,y1,x2,y2
    __shared__ float2 s_am[NGT];                     // area, mask
    __shared__ float s_part[4];

    int tid = threadIdx.x;
    int blockCell = blockIdx.x * 256;
    int gid = blockCell + tid;
    int b = gid / NPB;          // uniform within a block
    int r = gid % NPB;

    if (tid < NGT) {
        bool u8mode = det_mask_is_u8(gt_mask);
        float4 gtb = ((const float4*)gt_bboxes)[b * NGT + tid];
        float4 bx;
        bx.x = gtb.x - gtb.z * 0.5f;   // x1
        bx.y = gtb.y - gtb.w * 0.5f;   // y1
        bx.z = gtb.x + gtb.z * 0.5f;   // x2
        bx.w = gtb.y + gtb.w * 0.5f;   // y2
        s_box[tid] = bx;
        float2 am;
        am.x = gtb.z * gtb.w;
        am.y = det_mask_at(gt_mask, u8mode, b * NGT + tid) ? 1.0f : 0.0f;
        s_am[tid] = am;
    }
    __syncthreads();   // barrier #1 (of 2): GT tile staged

    // ---- Phase 1 head: loads + decode + pbbox store ----
    int a   = r / (NH * NW);
    int rem = r % (NH * NW);
    int j   = rem / NW;
    int i   = rem % NW;

    float4 tb = ((const float4*)t_bbox)[gid];
    float confl = conf_logits[gid];            // load early (older than DMAs)
    float s0 = det_sigmoid(tb.x), s1 = det_sigmoid(tb.y);
    float s2 = det_sigmoid(tb.z), s3 = det_sigmoid(tb.w);
    float px = (s0 * 2.0f - 0.5f + (float)i) * 8.0f;
    float py = (s1 * 2.0f - 0.5f + (float)j) * 8.0f;
    float sw = s2 * 2.0f, sh = s3 * 2.0f;
    float pw = sw * sw * det_aw3(a);
    float ph = sh * sh * det_ah3(a);
    float4 pb; pb.x = px; pb.y = py; pb.z = pw; pb.w = ph;
    ((float4*)out)[gid] = pb;

    // ---- Issue phase-2 tiles 0 and 1 now: HBM latency hides under IoU ----
    int w = tid >> 6, l = tid & 63;
    int cl_ = l >> 2;            // local cell within 16-row tile
    int q   = l & 3;             // quad lane: scans cols [5q, 5q+5)
    const float4* g4 = (const float4*)cls_logits;
    int wbase = blockCell + w * 64;            // first cell of this wave
    float4* t0 = &s_cls[w][0][0];
    float4* t1 = &s_cls[w][1][0];
    __builtin_amdgcn_sched_barrier(0);
    det_issue_tile(g4, t0, (size_t)(wbase +  0) * F4_PER_ROW, l);   // L0: 5 ops
    det_issue_tile(g4, t1, (size_t)(wbase + 16) * F4_PER_ROW, l);   // L1: 5 ops
    __builtin_amdgcn_sched_barrier(0);

    // ---- Phase 1 tail: IoU + conf BCE + block reduce ----
    float px1 = px - pw * 0.5f, px2 = px + pw * 0.5f;
    float py1 = py - ph * 0.5f, py2 = py + ph * 0.5f;
    float parea = pw * ph;
    float maxiou = 0.0f;
#pragma unroll
    for (int g = 0; g < NGT; g++) {
        float4 bx = s_box[g];
        float2 am = s_am[g];
        float iw = fmaxf(fminf(px2, bx.z) - fmaxf(px1, bx.x), 0.0f);
        float ih = fmaxf(fminf(py2, bx.w) - fmaxf(py1, bx.y), 0.0f);
        float inter = iw * ih;
        float uni = parea + am.x - inter;
        float iou = inter / (uni + 1e-16f);
        maxiou = fmaxf(maxiou, (am.y != 0.0f) ? iou : 0.0f);
    }

    float sconf = det_sigmoid(confl);          // kept for phase 2 via shuffle
    float lconf = det_bce(confl, maxiou);

    // Block 0 carries the GT target losses (extra VMEM here only makes the
    // phase-2 waits more conservative for block 0 — still correct).
    if (blockIdx.x == 0)
        lconf += det_gt_loss(tid, t_bbox, cls_logits, gt_bboxes, gt_cls, gt_mask);

#pragma unroll
    for (int off = 32; off > 0; off >>= 1) lconf += __shfl_down(lconf, off, 64);
    if (l == 0) s_part[w] = lconf;   // consumed after the final barrier

    // ---- Phase 2: 4 tiles, double-buffered DMA, counted waits, no barriers -
    DET_WAITVM(5);                                            // L0 done (L1 in flight)
    det_scan_tile(t0, cl_, q, wbase +  0, sconf, 0, out);
    __builtin_amdgcn_sched_barrier(0);
    det_issue_tile(g4, t0, (size_t)(wbase + 32) * F4_PER_ROW, l);   // L2
    DET_WAITVM(5);                                            // L1 done (L2 in flight)
    det_scan_tile(t1, cl_, q, wbase + 16, sconf, 1, out);
    __builtin_amdgcn_sched_barrier(0);
    det_issue_tile(g4, t1, (size_t)(wbase + 48) * F4_PER_ROW, l);   // L3
    DET_WAITVM(5);                                            // L2 done (L3 in flight)
    det_scan_tile(t0, cl_, q, wbase + 32, sconf, 2, out);
    DET_WAITVM(0);                                            // L3 done (pipeline end)
    det_scan_tile(t1, cl_, q, wbase + 48, sconf, 3, out);

    // ---- Epilogue: block partial -> device atomic --------------------------
    __syncthreads();   // barrier #2 (of 2): s_part ready
    if (tid == 0)
        atomicAdd(&g_acc, s_part[0] + s_part[1] + s_part[2] + s_part[3]);
}

// ---------------- Finalize: write loss, reset accumulator ------------------
__global__ void det_fin_k(float* __restrict__ out) {
    out[OFF_LOSS] = g_acc * (1.0f / NB);
    g_acc = 0.0f;
}

extern "C" void kernel_launch(void* const* d_in, const int* in_sizes, int n_in,
                              void* d_out, int out_size, void* d_ws, size_t ws_size,
                              hipStream_t stream) {
    (void)in_sizes; (void)n_in; (void)out_size; (void)d_ws; (void)ws_size;
    const float* t_bbox      = (const float*)d_in[0];
    const float* conf_logits = (const float*)d_in[1];
    const float* cls_logits  = (const float*)d_in[2];
    const float* gt_bboxes   = (const float*)d_in[3];
    const int*   gt_cls      = (const int*)d_in[4];
    const void*  gt_mask     = (const void*)d_in[5];  // layout auto-detected
    float* out = (float*)d_out;                       // float32 per reference

    det_all_k<<<NBLK, 256, 0, stream>>>(t_bbox, conf_logits, cls_logits,
                                        gt_bboxes, gt_cls, gt_mask, out);
    det_fin_k<<<1, 1, 0, stream>>>(out);
}